// Round 4
// baseline (323.858 us; speedup 1.0000x reference)
//
#include <hip/hip_runtime.h>

constexpr int B_ = 16, T_ = 1024, K_ = 1024;
constexpr float LOG2E_ = 1.4426950408889634f;
constexpr float LN2_   = 0.6931471805599453f;

__device__ __forceinline__ float warp_sum(float v) {
#pragma unroll
  for (int m = 1; m < 64; m <<= 1) v += __shfl_xor(v, m, 64);
  return v;
}

// tree-sum of 16 values (depth 4) without destroying the input
__device__ __forceinline__ float sum16(const float v[16]) {
  float t[16];
#pragma unroll
  for (int i = 0; i < 16; ++i) t[i] = v[i];
#pragma unroll
  for (int st = 1; st < 16; st <<= 1) {
#pragma unroll
    for (int i = 0; i < 16; i += 2 * st) t[i] += t[i + st];
  }
  return t[0];
}

// ---- DPP wave64 sum -> scalar broadcast (ctrl must be constexpr) ----
template <int CTRL>
__device__ __forceinline__ float dpp_add(float v) {
  int t = __builtin_amdgcn_update_dpp(0, __builtin_bit_cast(int, v), CTRL, 0xF, 0xF, true);
  return v + __builtin_bit_cast(float, t);
}
__device__ __forceinline__ float wave_sum64_dpp(float v) {
  v = dpp_add<0x111>(v);  // row_shr:1
  v = dpp_add<0x112>(v);  // row_shr:2
  v = dpp_add<0x114>(v);  // row_shr:4
  v = dpp_add<0x118>(v);  // row_shr:8  -> lanes 15/31/47/63 hold row sums
  v = dpp_add<0x142>(v);  // row_bcast:15
  v = dpp_add<0x143>(v);  // row_bcast:31 -> lane 63 = total
  return __builtin_bit_cast(float, __builtin_amdgcn_readlane(__builtin_bit_cast(int, v), 63));
}

// ---------------------------------------------------------------------------
// Emission kernel: F[b,t,k] = offd * exp(-0.5 (o-mu)^2 / sigma^2 - ln_sigma)
// (row-constant -0.5*ln(2pi) cancels in gamma; offd folded in for the
// recurrence's fma form). One block per (b,t).
// ---------------------------------------------------------------------------
extern "C" __global__ void __launch_bounds__(256)
hmm_emit(const float* __restrict__ obvs, const float* __restrict__ mu,
         const float* __restrict__ ln_sigma, const float* __restrict__ ln_A,
         float* __restrict__ F) {
  const int bt = blockIdx.x;           // b*T + t
  const float o = obvs[bt];
  const float offd = __expf(ln_A[1]);
  const float lof = __builtin_amdgcn_logf(offd);  // log2(offd)
  const int k0 = threadIdx.x * 4;
  const float4 m  = *reinterpret_cast<const float4*>(mu + k0);
  const float4 ls = *reinterpret_cast<const float4*>(ln_sigma + k0);
  float4 e;
  {
    const float iv0 = __builtin_amdgcn_exp2f(-2.0f * ls.x * LOG2E_);
    const float iv1 = __builtin_amdgcn_exp2f(-2.0f * ls.y * LOG2E_);
    const float iv2 = __builtin_amdgcn_exp2f(-2.0f * ls.z * LOG2E_);
    const float iv3 = __builtin_amdgcn_exp2f(-2.0f * ls.w * LOG2E_);
    const float d0 = o - m.x, d1 = o - m.y, d2 = o - m.z, d3 = o - m.w;
    // exp2(log2(offd) + (-0.5 d^2 iv - ls)*log2e)
    e.x = __builtin_amdgcn_exp2f(__builtin_fmaf(d0 * d0, -0.5f * iv0 * LOG2E_, lof - ls.x * LOG2E_));
    e.y = __builtin_amdgcn_exp2f(__builtin_fmaf(d1 * d1, -0.5f * iv1 * LOG2E_, lof - ls.y * LOG2E_));
    e.z = __builtin_amdgcn_exp2f(__builtin_fmaf(d2 * d2, -0.5f * iv2 * LOG2E_, lof - ls.z * LOG2E_));
    e.w = __builtin_amdgcn_exp2f(__builtin_fmaf(d3 * d3, -0.5f * iv3 * LOG2E_, lof - ls.w * LOG2E_));
  }
  *reinterpret_cast<float4*>(F + (size_t)bt * K_ + k0) = e;
}

// ---------------------------------------------------------------------------
// Recurrences, restructured:
//   forward:  inner_{t+1} = F_{t+1} o fma(s, inner_t, 1),
//             s = (dmo/offd) * rcp(Sum inner_t)          [inner_t ~ alpha_t]
//   backward: u = F_{t+1} o innerB_{t+1};
//             innerB_t = fma(sB, u, 1), sB = (dmo/offd)*rcp(Sum u)
// Ring depth 4 / unroll 4 keeps vmem-ops between a ring load's issue and its
// wait at 24 (< vmcnt 63 max) so waits never include newer HBM stores.
// Blocks 0..15 forward, 16..31 backward.
// ---------------------------------------------------------------------------
extern "C" __global__ void __launch_bounds__(64, 1)
hmm_recur2(const float* __restrict__ F, const float* __restrict__ ln_pi,
           const float* __restrict__ ln_A,
           float* __restrict__ alpha_out, float* __restrict__ beta_out) {
  const int lane = threadIdx.x;
  const int b   = blockIdx.x & (B_ - 1);
  const int dir = blockIdx.x >> 4;

  float pi[16];
#pragma unroll
  for (int i = 0; i < 16; ++i) pi[i] = __expf(ln_pi[lane * 16 + i]);
  const float offd = __expf(ln_A[1]);
  const float dmo  = __expf(ln_A[0]) - offd;
  const float ds   = dmo / offd;

  const float4* Frow = reinterpret_cast<const float4*>(F + (size_t)b * T_ * K_) + lane * 4;
  const int RS = K_ / 4;  // float4 row stride

  float4 eb[4][4];  // prefetch ring (64 VGPRs)
  float inner[16];

  if (dir == 0) {
    float4* Arow = reinterpret_cast<float4*>(alpha_out + (size_t)b * T_ * K_) + lane * 4;
    // t=0: inner = pi o F0 (prop. to alpha_0), store
    {
      float4 h[4];
#pragma unroll
      for (int q = 0; q < 4; ++q) h[q] = Frow[q];
      const float* hf = reinterpret_cast<const float*>(h);
#pragma unroll
      for (int i = 0; i < 16; ++i) inner[i] = pi[i] * hf[i];
      float4 v0 = {inner[0], inner[1], inner[2], inner[3]},   v1 = {inner[4], inner[5], inner[6], inner[7]};
      float4 v2 = {inner[8], inner[9], inner[10], inner[11]}, v3 = {inner[12], inner[13], inner[14], inner[15]};
      Arow[0] = v0; Arow[1] = v1; Arow[2] = v2; Arow[3] = v3;
    }
    // prefetch rows 1..4
#pragma unroll
    for (int j = 0; j < 4; ++j) {
      const float4* src = Frow + (size_t)(1 + j) * RS;
#pragma unroll
      for (int q = 0; q < 4; ++q) eb[j][q] = src[q];
    }
    for (int tt = 0; tt < T_ / 4; ++tt) {
#pragma unroll
      for (int j = 0; j < 4; ++j) {
        const int t = 1 + tt * 4 + j;  // 1..1024 (t==1024 dead)
        const float S = wave_sum64_dpp(sum16(inner));
        const float s = ds * __builtin_amdgcn_rcpf(S);
        const float* ef = reinterpret_cast<const float*>(eb[j]);
#pragma unroll
        for (int i = 0; i < 16; ++i) inner[i] = ef[i] * __builtin_fmaf(s, inner[i], 1.0f);
        if (t < T_) {
          float4* dst = Arow + (size_t)t * RS;
          float4 v0 = {inner[0], inner[1], inner[2], inner[3]},   v1 = {inner[4], inner[5], inner[6], inner[7]};
          float4 v2 = {inner[8], inner[9], inner[10], inner[11]}, v3 = {inner[12], inner[13], inner[14], inner[15]};
          dst[0] = v0; dst[1] = v1; dst[2] = v2; dst[3] = v3;
        }
        const int rp = (t + 4 < T_) ? (t + 4) : (T_ - 1);
        const float4* src = Frow + (size_t)rp * RS;
#pragma unroll
        for (int q = 0; q < 4; ++q) eb[j][q] = src[q];
      }
    }
  } else {
    float4* Brow = reinterpret_cast<float4*>(beta_out + (size_t)b * T_ * K_) + lane * 4;
    // t=T-1: innerB = pi (prop. to beta_{T-1}), store
#pragma unroll
    for (int i = 0; i < 16; ++i) inner[i] = pi[i];
    {
      float4* dst = Brow + (size_t)(T_ - 1) * RS;
      float4 v0 = {inner[0], inner[1], inner[2], inner[3]},   v1 = {inner[4], inner[5], inner[6], inner[7]};
      float4 v2 = {inner[8], inner[9], inner[10], inner[11]}, v3 = {inner[12], inner[13], inner[14], inner[15]};
      dst[0] = v0; dst[1] = v1; dst[2] = v2; dst[3] = v3;
    }
    // step k consumes F row T-1-k; prefetch rows T-1..T-4
#pragma unroll
    for (int j = 0; j < 4; ++j) {
      const float4* src = Frow + (size_t)(T_ - 1 - j) * RS;
#pragma unroll
      for (int q = 0; q < 4; ++q) eb[j][q] = src[q];
    }
    for (int kk = 0; kk < T_ / 4; ++kk) {
#pragma unroll
      for (int j = 0; j < 4; ++j) {
        const int k = kk * 4 + j;  // 0..1023 (k==1023 dead)
        const float* ef = reinterpret_cast<const float*>(eb[j]);
        float u[16];
#pragma unroll
        for (int i = 0; i < 16; ++i) u[i] = ef[i] * inner[i];
        const float Su = wave_sum64_dpp(sum16(u));
        const float sB = ds * __builtin_amdgcn_rcpf(Su);
#pragma unroll
        for (int i = 0; i < 16; ++i) inner[i] = __builtin_fmaf(sB, u[i], 1.0f);
        if (k < T_ - 1) {
          float4* dst = Brow + (size_t)(T_ - 2 - k) * RS;
          float4 v0 = {inner[0], inner[1], inner[2], inner[3]},   v1 = {inner[4], inner[5], inner[6], inner[7]};
          float4 v2 = {inner[8], inner[9], inner[10], inner[11]}, v3 = {inner[12], inner[13], inner[14], inner[15]};
          dst[0] = v0; dst[1] = v1; dst[2] = v2; dst[3] = v3;
        }
        const int rp = (T_ - 1 - k - 4 > 0) ? (T_ - 1 - k - 4) : 0;
        const float4* src = Frow + (size_t)rp * RS;
#pragma unroll
        for (int q = 0; q < 4; ++q) eb[j][q] = src[q];
      }
    }
  }
}

// ---------------------------------------------------------------------------
// gamma = log(alpha*beta) - log(sum_k alpha*beta), one wave per (b,t) row.
// ---------------------------------------------------------------------------
extern "C" __global__ void __launch_bounds__(256, 4)
hmm_gamma(const float* __restrict__ alpha, const float* __restrict__ beta,
          float* __restrict__ outp) {
  const int lane = threadIdx.x & 63;
  const int wid  = threadIdx.x >> 6;
  const int row  = blockIdx.x * 4 + wid;
  const size_t base = (size_t)row * K_ + lane * 16;
  const float4* ap = reinterpret_cast<const float4*>(alpha + base);
  const float4* bp = reinterpret_cast<const float4*>(beta + base);
  float4* op = reinterpret_cast<float4*>(outp + base);

  float p[16];
#pragma unroll
  for (int j = 0; j < 4; ++j) {
    const float4 av = ap[j], bv = bp[j];
    p[4 * j + 0] = av.x * bv.x;
    p[4 * j + 1] = av.y * bv.y;
    p[4 * j + 2] = av.z * bv.z;
    p[4 * j + 3] = av.w * bv.w;
  }
  const float S   = warp_sum(sum16(p));
  const float nls = -__builtin_amdgcn_logf(S) * LN2_;
#pragma unroll
  for (int j = 0; j < 4; ++j) {
    float4 ov;
    ov.x = __builtin_fmaf(__builtin_amdgcn_logf(p[4 * j + 0]), LN2_, nls);
    ov.y = __builtin_fmaf(__builtin_amdgcn_logf(p[4 * j + 1]), LN2_, nls);
    ov.z = __builtin_fmaf(__builtin_amdgcn_logf(p[4 * j + 2]), LN2_, nls);
    ov.w = __builtin_fmaf(__builtin_amdgcn_logf(p[4 * j + 3]), LN2_, nls);
    op[j] = ov;
  }
}

// ===========================================================================
// Fallback kernels (R0 structure, known-good) for small workspaces.
// ===========================================================================
extern "C" __global__ void __launch_bounds__(64, 1)
hmm_recur_fused(const float* __restrict__ obvs, const float* __restrict__ mu,
                const float* __restrict__ ln_sigma, const float* __restrict__ ln_pi,
                const float* __restrict__ ln_A,
                float* __restrict__ alpha_out, float* __restrict__ beta_out) {
  const int lane = threadIdx.x;
  const int b   = blockIdx.x & (B_ - 1);
  const int dir = blockIdx.x >> 4;

  __shared__ float so[T_];
  {
    const float4* src = reinterpret_cast<const float4*>(obvs + (size_t)b * T_);
    float4* dst = reinterpret_cast<float4*>(so);
#pragma unroll
    for (int j = 0; j < T_ / (4 * 64); ++j) dst[lane + j * 64] = src[lane + j * 64];
  }
  __syncthreads();

  float muv[16], niv[16], cc[16], pi[16];
#pragma unroll
  for (int i = 0; i < 16; ++i) {
    const int k = lane * 16 + i;
    const float m = mu[k], ls = ln_sigma[k];
    const float iv = __expf(-2.0f * ls);
    muv[i] = m; niv[i] = -0.5f * iv * LOG2E_; cc[i] = -ls * LOG2E_;
    pi[i] = __expf(ln_pi[k]);
  }
  const float offd = __expf(ln_A[1]);
  const float dmo  = __expf(ln_A[0]) - offd;

  if (dir == 0) {
    float a[16];
#pragma unroll
    for (int i = 0; i < 16; ++i) a[i] = (pi[i] - offd) / dmo;
    float4* dst = reinterpret_cast<float4*>(alpha_out + (size_t)b * T_ * K_) + lane * 4;
    float o = so[0];
    for (int t = 0; t < T_; ++t) {
      const float onext = so[(t + 1) & (T_ - 1)];
      float ah[16];
#pragma unroll
      for (int i = 0; i < 16; ++i) {
        const float d = o - muv[i];
        const float e = __builtin_amdgcn_exp2f(__builtin_fmaf(d * d, niv[i], cc[i]));
        ah[i] = e * __builtin_fmaf(a[i], dmo, offd);
      }
      const float S = warp_sum(sum16(ah));
      const float r = __builtin_amdgcn_rcpf(S);
#pragma unroll
      for (int i = 0; i < 16; ++i) a[i] = ah[i] * r;
      float4 v0 = {a[0], a[1], a[2], a[3]},   v1 = {a[4], a[5], a[6], a[7]};
      float4 v2 = {a[8], a[9], a[10], a[11]}, v3 = {a[12], a[13], a[14], a[15]};
      dst[0] = v0; dst[1] = v1; dst[2] = v2; dst[3] = v3;
      dst += K_ / 4;
      o = onext;
    }
  } else {
    float bc[16];
#pragma unroll
    for (int i = 0; i < 16; ++i) bc[i] = pi[i];
    const float sumA = __builtin_fmaf((float)K_, offd, dmo);
    const float q = offd / sumA;
    float4* dst = reinterpret_cast<float4*>(beta_out + ((size_t)b * T_ + (T_ - 1)) * K_) + lane * 4;
    {
      float4 v0 = {bc[0], bc[1], bc[2], bc[3]},   v1 = {bc[4], bc[5], bc[6], bc[7]};
      float4 v2 = {bc[8], bc[9], bc[10], bc[11]}, v3 = {bc[12], bc[13], bc[14], bc[15]};
      dst[0] = v0; dst[1] = v1; dst[2] = v2; dst[3] = v3;
    }
    float o = so[T_ - 1];
    for (int t = T_ - 2; t >= 0; --t) {
      const float onext = so[t];
      float u[16];
#pragma unroll
      for (int i = 0; i < 16; ++i) {
        const float d = o - muv[i];
        const float e = __builtin_amdgcn_exp2f(__builtin_fmaf(d * d, niv[i], cc[i]));
        u[i] = e * bc[i];
      }
      const float Su = warp_sum(sum16(u));
      const float r = __builtin_amdgcn_rcpf(Su * sumA);
      const float coef = dmo * r;
#pragma unroll
      for (int i = 0; i < 16; ++i) bc[i] = __builtin_fmaf(u[i], coef, q);
      dst -= K_ / 4;
      float4 v0 = {bc[0], bc[1], bc[2], bc[3]},   v1 = {bc[4], bc[5], bc[6], bc[7]};
      float4 v2 = {bc[8], bc[9], bc[10], bc[11]}, v3 = {bc[12], bc[13], bc[14], bc[15]};
      dst[0] = v0; dst[1] = v1; dst[2] = v2; dst[3] = v3;
      o = onext;
    }
  }
}

extern "C" __global__ void __launch_bounds__(64, 1)
hmm_bwd_gamma(const float* __restrict__ obvs, const float* __restrict__ mu,
              const float* __restrict__ ln_sigma, const float* __restrict__ ln_pi,
              const float* __restrict__ ln_A, float* __restrict__ io) {
  const int lane = threadIdx.x;
  const int b = blockIdx.x;

  __shared__ float so[T_];
  {
    const float4* src = reinterpret_cast<const float4*>(obvs + (size_t)b * T_);
    float4* dst = reinterpret_cast<float4*>(so);
#pragma unroll
    for (int j = 0; j < T_ / (4 * 64); ++j) dst[lane + j * 64] = src[lane + j * 64];
  }
  __syncthreads();

  float muv[16], niv[16], cc[16], pi[16];
#pragma unroll
  for (int i = 0; i < 16; ++i) {
    const int k = lane * 16 + i;
    const float m = mu[k], ls = ln_sigma[k];
    const float iv = __expf(-2.0f * ls);
    muv[i] = m; niv[i] = -0.5f * iv * LOG2E_; cc[i] = -ls * LOG2E_;
    pi[i] = __expf(ln_pi[k]);
  }
  const float offd = __expf(ln_A[1]);
  const float dmo  = __expf(ln_A[0]) - offd;
  const float sumA = __builtin_fmaf((float)K_, offd, dmo);
  const float q = offd / sumA;

  float bc[16];
#pragma unroll
  for (int i = 0; i < 16; ++i) bc[i] = pi[i];

  float4* gp = reinterpret_cast<float4*>(io + ((size_t)b * T_ + (T_ - 1)) * K_) + lane * 4;
  {
    float4 a0 = gp[0], a1 = gp[1], a2 = gp[2], a3 = gp[3];
    float p[16] = {a0.x * bc[0],  a0.y * bc[1],  a0.z * bc[2],  a0.w * bc[3],
                   a1.x * bc[4],  a1.y * bc[5],  a1.z * bc[6],  a1.w * bc[7],
                   a2.x * bc[8],  a2.y * bc[9],  a2.z * bc[10], a2.w * bc[11],
                   a3.x * bc[12], a3.y * bc[13], a3.z * bc[14], a3.w * bc[15]};
    const float Sp  = warp_sum(sum16(p));
    const float nls = -__builtin_amdgcn_logf(Sp) * LN2_;
    float g[16];
#pragma unroll
    for (int i = 0; i < 16; ++i) g[i] = __builtin_fmaf(__builtin_amdgcn_logf(p[i]), LN2_, nls);
    float4 v0 = {g[0], g[1], g[2], g[3]},   v1 = {g[4], g[5], g[6], g[7]};
    float4 v2 = {g[8], g[9], g[10], g[11]}, v3 = {g[12], g[13], g[14], g[15]};
    gp[0] = v0; gp[1] = v1; gp[2] = v2; gp[3] = v3;
  }
  float o = so[T_ - 1];
  for (int t = T_ - 2; t >= 0; --t) {
    const float onext = so[t];
    gp -= K_ / 4;
    float4 a0 = gp[0], a1 = gp[1], a2 = gp[2], a3 = gp[3];
    float u[16];
#pragma unroll
    for (int i = 0; i < 16; ++i) {
      const float d = o - muv[i];
      const float e = __builtin_amdgcn_exp2f(__builtin_fmaf(d * d, niv[i], cc[i]));
      u[i] = e * bc[i];
    }
    const float Su = warp_sum(sum16(u));
    const float r = __builtin_amdgcn_rcpf(Su * sumA);
    const float coef = dmo * r;
#pragma unroll
    for (int i = 0; i < 16; ++i) bc[i] = __builtin_fmaf(u[i], coef, q);
    float p[16] = {a0.x * bc[0],  a0.y * bc[1],  a0.z * bc[2],  a0.w * bc[3],
                   a1.x * bc[4],  a1.y * bc[5],  a1.z * bc[6],  a1.w * bc[7],
                   a2.x * bc[8],  a2.y * bc[9],  a2.z * bc[10], a2.w * bc[11],
                   a3.x * bc[12], a3.y * bc[13], a3.z * bc[14], a3.w * bc[15]};
    const float Sp  = warp_sum(sum16(p));
    const float nls = -__builtin_amdgcn_logf(Sp) * LN2_;
    float g[16];
#pragma unroll
    for (int i = 0; i < 16; ++i) g[i] = __builtin_fmaf(__builtin_amdgcn_logf(p[i]), LN2_, nls);
    float4 v0 = {g[0], g[1], g[2], g[3]},   v1 = {g[4], g[5], g[6], g[7]};
    float4 v2 = {g[8], g[9], g[10], g[11]}, v3 = {g[12], g[13], g[14], g[15]};
    gp[0] = v0; gp[1] = v1; gp[2] = v2; gp[3] = v3;
    o = onext;
  }
}

extern "C" void kernel_launch(void* const* d_in, const int* in_sizes, int n_in,
                              void* d_out, int out_size, void* d_ws, size_t ws_size,
                              hipStream_t stream) {
  const float* obvs     = (const float*)d_in[0];
  const float* mu       = (const float*)d_in[1];
  const float* ln_sigma = (const float*)d_in[2];
  const float* ln_pi    = (const float*)d_in[3];
  const float* ln_A     = (const float*)d_in[4];
  float* out = (float*)d_out;

  const size_t plane = (size_t)B_ * T_ * K_;           // elements
  const size_t planeB = plane * sizeof(float);         // 67 MB

  if (ws_size >= 2 * planeB) {
    float* F    = (float*)d_ws;
    float* beta = (float*)d_ws + plane;
    hipLaunchKernelGGL(hmm_emit, dim3(B_ * T_), dim3(256), 0, stream,
                       obvs, mu, ln_sigma, ln_A, F);
    hipLaunchKernelGGL(hmm_recur2, dim3(32), dim3(64), 0, stream,
                       F, ln_pi, ln_A, out, beta);
    hipLaunchKernelGGL(hmm_gamma, dim3(B_ * T_ / 4), dim3(256), 0, stream,
                       out, beta, out);
  } else if (ws_size >= planeB) {
    float* beta = (float*)d_ws;
    hipLaunchKernelGGL(hmm_recur_fused, dim3(32), dim3(64), 0, stream,
                       obvs, mu, ln_sigma, ln_pi, ln_A, out, beta);
    hipLaunchKernelGGL(hmm_gamma, dim3(B_ * T_ / 4), dim3(256), 0, stream,
                       out, beta, out);
  } else {
    hipLaunchKernelGGL(hmm_recur_fused, dim3(16), dim3(64), 0, stream,
                       obvs, mu, ln_sigma, ln_pi, ln_A, out, out);
    hipLaunchKernelGGL(hmm_bwd_gamma, dim3(16), dim3(64), 0, stream,
                       obvs, mu, ln_sigma, ln_pi, ln_A, out);
  }
}

// Round 5
// 275.431 us; speedup vs baseline: 1.1758x; 1.1758x over previous
//
#include <hip/hip_runtime.h>

constexpr int B_ = 16, T_ = 1024, K_ = 1024;
constexpr int CH_ = 32;              // reconstruction chunk length
constexpr int NC_ = T_ / CH_;        // 32 chunks per (b, dir)
constexpr float LOG2E_ = 1.4426950408889634f;
constexpr float LN2_   = 0.6931471805599453f;

__device__ __forceinline__ float warp_sum(float v) {
#pragma unroll
  for (int m = 1; m < 64; m <<= 1) v += __shfl_xor(v, m, 64);
  return v;
}

// tree-sum of 16 values (depth 4) without destroying the input
__device__ __forceinline__ float sum16(const float v[16]) {
  float t[16];
#pragma unroll
  for (int i = 0; i < 16; ++i) t[i] = v[i];
#pragma unroll
  for (int st = 1; st < 16; st <<= 1) {
#pragma unroll
    for (int i = 0; i < 16; i += 2 * st) t[i] += t[i + st];
  }
  return t[0];
}

// ---- DPP wave64 sum -> scalar broadcast (ctrl must be constexpr) ----
template <int CTRL>
__device__ __forceinline__ float dpp_add(float v) {
  int t = __builtin_amdgcn_update_dpp(0, __builtin_bit_cast(int, v), CTRL, 0xF, 0xF, true);
  return v + __builtin_bit_cast(float, t);
}
__device__ __forceinline__ float wave_sum64_dpp(float v) {
  v = dpp_add<0x111>(v);  // row_shr:1
  v = dpp_add<0x112>(v);  // row_shr:2
  v = dpp_add<0x114>(v);  // row_shr:4
  v = dpp_add<0x118>(v);  // row_shr:8  -> lanes 15/31/47/63 hold row sums
  v = dpp_add<0x142>(v);  // row_bcast:15
  v = dpp_add<0x143>(v);  // row_bcast:31 -> lane 63 = total
  return __builtin_bit_cast(float, __builtin_amdgcn_readlane(__builtin_bit_cast(int, v), 63));
}

// ---------------------------------------------------------------------------
// Emission: F[b,t,k] = offd * exp(-0.5 (o-mu)^2 / sigma^2 - ln_sigma)
// (row-constant -0.5*ln(2pi) cancels in gamma; offd folded in). Block per (b,t).
// ---------------------------------------------------------------------------
extern "C" __global__ void __launch_bounds__(256)
hmm_emit(const float* __restrict__ obvs, const float* __restrict__ mu,
         const float* __restrict__ ln_sigma, const float* __restrict__ ln_A,
         float* __restrict__ F) {
  const int bt = blockIdx.x;           // b*T + t
  const float o = obvs[bt];
  const float offd = __expf(ln_A[1]);
  const float lof = __builtin_amdgcn_logf(offd);  // log2(offd)
  const int k0 = threadIdx.x * 4;
  const float4 m  = *reinterpret_cast<const float4*>(mu + k0);
  const float4 ls = *reinterpret_cast<const float4*>(ln_sigma + k0);
  float4 e;
  {
    const float iv0 = __builtin_amdgcn_exp2f(-2.0f * ls.x * LOG2E_);
    const float iv1 = __builtin_amdgcn_exp2f(-2.0f * ls.y * LOG2E_);
    const float iv2 = __builtin_amdgcn_exp2f(-2.0f * ls.z * LOG2E_);
    const float iv3 = __builtin_amdgcn_exp2f(-2.0f * ls.w * LOG2E_);
    const float d0 = o - m.x, d1 = o - m.y, d2 = o - m.z, d3 = o - m.w;
    e.x = __builtin_amdgcn_exp2f(__builtin_fmaf(d0 * d0, -0.5f * iv0 * LOG2E_, lof - ls.x * LOG2E_));
    e.y = __builtin_amdgcn_exp2f(__builtin_fmaf(d1 * d1, -0.5f * iv1 * LOG2E_, lof - ls.y * LOG2E_));
    e.z = __builtin_amdgcn_exp2f(__builtin_fmaf(d2 * d2, -0.5f * iv2 * LOG2E_, lof - ls.z * LOG2E_));
    e.w = __builtin_amdgcn_exp2f(__builtin_fmaf(d3 * d3, -0.5f * iv3 * LOG2E_, lof - ls.w * LOG2E_));
  }
  *reinterpret_cast<float4*>(F + (size_t)bt * K_ + k0) = e;
}

// ---------------------------------------------------------------------------
// Serial scalar kernel: fwd (dir 0) / bwd (dir 1) recurrences in registers.
// Emits per-step scalars sf/sb and a checkpoint row every CH_ steps, written
// directly into the alpha (d_out) / beta planes. No bulk stores in the loop.
//   fwd: inner_{t+1} = F_{t+1} o fma(sf[t], inner_t, 1), sf[t]=ds*rcp(Sum inner_t)
//   bwd: u = F_{t+1} o inner_{t+1}; inner_t = fma(sb[t], u, 1), sb[t]=ds*rcp(Sum u)
// ---------------------------------------------------------------------------
extern "C" __global__ void __launch_bounds__(64, 1)
hmm_scal(const float* __restrict__ F, const float* __restrict__ ln_pi,
         const float* __restrict__ ln_A,
         float* __restrict__ sf, float* __restrict__ sb,
         float* __restrict__ alpha_out, float* __restrict__ beta_out) {
  const int lane = threadIdx.x;
  const int b   = blockIdx.x & (B_ - 1);
  const int dir = blockIdx.x >> 4;

  float pi[16];
#pragma unroll
  for (int i = 0; i < 16; ++i) pi[i] = __expf(ln_pi[lane * 16 + i]);
  const float offd = __expf(ln_A[1]);
  const float dmo  = __expf(ln_A[0]) - offd;
  const float ds   = dmo / offd;

  const float4* Frow = reinterpret_cast<const float4*>(F + (size_t)b * T_ * K_) + lane * 4;
  const int RS = K_ / 4;  // float4 row stride

  float4 eb[8][4];  // prefetch ring
  float inner[16];

  if (dir == 0) {
    float4* Arow = reinterpret_cast<float4*>(alpha_out + (size_t)b * T_ * K_) + lane * 4;
    float* sfb = sf + b * T_;
    // inner_0 = pi o F_0
    {
      float4 h[4];
#pragma unroll
      for (int q = 0; q < 4; ++q) h[q] = Frow[q];
      const float* hf = reinterpret_cast<const float*>(h);
#pragma unroll
      for (int i = 0; i < 16; ++i) inner[i] = pi[i] * hf[i];
    }
    // ring prologue: rows 1..8
#pragma unroll
    for (int j = 0; j < 8; ++j) {
      const float4* src = Frow + (size_t)(1 + j) * RS;
#pragma unroll
      for (int q = 0; q < 4; ++q) eb[j][q] = src[q];
    }
    for (int tt = 0; tt < T_ / 8; ++tt) {
#pragma unroll
      for (int j = 0; j < 8; ++j) {
        const int t = tt * 8 + j;  // 0..1023; t==1023 update is dead
        if ((t & (CH_ - 1)) == 0) {  // checkpoint inner_t -> alpha row t
          float4* dst = Arow + (size_t)t * RS;
          float4 v0 = {inner[0], inner[1], inner[2], inner[3]},   v1 = {inner[4], inner[5], inner[6], inner[7]};
          float4 v2 = {inner[8], inner[9], inner[10], inner[11]}, v3 = {inner[12], inner[13], inner[14], inner[15]};
          dst[0] = v0; dst[1] = v1; dst[2] = v2; dst[3] = v3;
        }
        const float S = wave_sum64_dpp(sum16(inner));
        const float s = ds * __builtin_amdgcn_rcpf(S);
        if (lane == 0) sfb[t] = s;
        const float* ef = reinterpret_cast<const float*>(eb[j]);
#pragma unroll
        for (int i = 0; i < 16; ++i) inner[i] = ef[i] * __builtin_fmaf(s, inner[i], 1.0f);
        const int rp = (t + 9 < T_) ? (t + 9) : (T_ - 1);
        const float4* src = Frow + (size_t)rp * RS;
#pragma unroll
        for (int q = 0; q < 4; ++q) eb[j][q] = src[q];
      }
    }
  } else {
    float4* Brow = reinterpret_cast<float4*>(beta_out + (size_t)b * T_ * K_) + lane * 4;
    float* sbb = sb + b * T_;
#pragma unroll
    for (int i = 0; i < 16; ++i) inner[i] = pi[i];  // innerB_{T-1}
    // ring prologue: rows 1023..1016 (step i consumes F row 1023-i)
#pragma unroll
    for (int j = 0; j < 8; ++j) {
      const float4* src = Frow + (size_t)(T_ - 1 - j) * RS;
#pragma unroll
      for (int q = 0; q < 4; ++q) eb[j][q] = src[q];
    }
    for (int tt = 0; tt < T_ / 8; ++tt) {
#pragma unroll
      for (int j = 0; j < 8; ++j) {
        const int i_ = tt * 8 + j;
        const int t = T_ - 1 - i_;  // 1023..0; t==0 update is dead
        if ((t & (CH_ - 1)) == (CH_ - 1)) {  // checkpoint innerB_t -> beta row t
          float4* dst = Brow + (size_t)t * RS;
          float4 v0 = {inner[0], inner[1], inner[2], inner[3]},   v1 = {inner[4], inner[5], inner[6], inner[7]};
          float4 v2 = {inner[8], inner[9], inner[10], inner[11]}, v3 = {inner[12], inner[13], inner[14], inner[15]};
          dst[0] = v0; dst[1] = v1; dst[2] = v2; dst[3] = v3;
        }
        const float* ef = reinterpret_cast<const float*>(eb[j]);
        float u[16];
#pragma unroll
        for (int i = 0; i < 16; ++i) u[i] = ef[i] * inner[i];
        const float Su = wave_sum64_dpp(sum16(u));
        const float s = ds * __builtin_amdgcn_rcpf(Su);
        const int idx = (t > 0) ? (t - 1) : (T_ - 1);  // t==0: dummy slot
        if (lane == 0) sbb[idx] = s;
#pragma unroll
        for (int i = 0; i < 16; ++i) inner[i] = __builtin_fmaf(s, u[i], 1.0f);
        const int rp = (t - 8 > 0) ? (t - 8) : 0;
        const float4* src = Frow + (size_t)rp * RS;
#pragma unroll
        for (int q = 0; q < 4; ++q) eb[j][q] = src[q];
      }
    }
  }
}

// ---------------------------------------------------------------------------
// Parallel reconstruction: each block replays one CH_-step chunk of one (b,dir)
// chain from its checkpoint, streaming F and writing alpha/beta rows.
// Fully parallel across 1024 blocks; per-element chain is fma+mul only.
// ---------------------------------------------------------------------------
extern "C" __global__ void __launch_bounds__(256, 4)
hmm_recon(const float* __restrict__ F, const float* __restrict__ sf,
          const float* __restrict__ sb,
          float* __restrict__ alpha, float* __restrict__ beta) {
  const int c   = blockIdx.x & (NC_ - 1);
  const int b   = (blockIdx.x >> 5) & (B_ - 1);
  const int dir = blockIdx.x >> 9;
  const int tid = threadIdx.x;  // float4 column index 0..255
  const int t0  = c * CH_;

  __shared__ float sl[CH_];
  const float4* Fb = reinterpret_cast<const float4*>(F + (size_t)b * T_ * K_);
  const int RS = K_ / 4;

  if (dir == 0) {
    if (tid < CH_ - 1) sl[tid] = sf[b * T_ + t0 + tid];
    __syncthreads();
    float4* Ab = reinterpret_cast<float4*>(alpha + (size_t)b * T_ * K_);
    float4 a = Ab[(size_t)t0 * RS + tid];  // checkpoint row (written by hmm_scal)
#pragma unroll
    for (int j = 1; j < CH_; ++j) {
      const float4 f = Fb[(size_t)(t0 + j) * RS + tid];
      const float s = sl[j - 1];
      a.x = f.x * __builtin_fmaf(s, a.x, 1.0f);
      a.y = f.y * __builtin_fmaf(s, a.y, 1.0f);
      a.z = f.z * __builtin_fmaf(s, a.z, 1.0f);
      a.w = f.w * __builtin_fmaf(s, a.w, 1.0f);
      Ab[(size_t)(t0 + j) * RS + tid] = a;
    }
  } else {
    if (tid < CH_ - 1) sl[tid] = sb[b * T_ + t0 + tid];
    __syncthreads();
    const int th = t0 + CH_ - 1;
    float4* Bb = reinterpret_cast<float4*>(beta + (size_t)b * T_ * K_);
    float4 v = Bb[(size_t)th * RS + tid];  // checkpoint row
#pragma unroll
    for (int j = 1; j < CH_; ++j) {
      const int t = th - j;
      const float4 f = Fb[(size_t)(t + 1) * RS + tid];
      const float s = sl[t - t0];
      v.x = __builtin_fmaf(s, f.x * v.x, 1.0f);
      v.y = __builtin_fmaf(s, f.y * v.y, 1.0f);
      v.z = __builtin_fmaf(s, f.z * v.z, 1.0f);
      v.w = __builtin_fmaf(s, f.w * v.w, 1.0f);
      Bb[(size_t)t * RS + tid] = v;
    }
  }
}

// ---------------------------------------------------------------------------
// gamma = log(alpha*beta) - log(sum_k alpha*beta), one wave per (b,t) row.
// ---------------------------------------------------------------------------
extern "C" __global__ void __launch_bounds__(256, 4)
hmm_gamma(const float* __restrict__ alpha, const float* __restrict__ beta,
          float* __restrict__ outp) {
  const int lane = threadIdx.x & 63;
  const int wid  = threadIdx.x >> 6;
  const int row  = blockIdx.x * 4 + wid;
  const size_t base = (size_t)row * K_ + lane * 16;
  const float4* ap = reinterpret_cast<const float4*>(alpha + base);
  const float4* bp = reinterpret_cast<const float4*>(beta + base);
  float4* op = reinterpret_cast<float4*>(outp + base);

  float p[16];
#pragma unroll
  for (int j = 0; j < 4; ++j) {
    const float4 av = ap[j], bv = bp[j];
    p[4 * j + 0] = av.x * bv.x;
    p[4 * j + 1] = av.y * bv.y;
    p[4 * j + 2] = av.z * bv.z;
    p[4 * j + 3] = av.w * bv.w;
  }
  const float S   = warp_sum(sum16(p));
  const float nls = -__builtin_amdgcn_logf(S) * LN2_;
#pragma unroll
  for (int j = 0; j < 4; ++j) {
    float4 ov;
    ov.x = __builtin_fmaf(__builtin_amdgcn_logf(p[4 * j + 0]), LN2_, nls);
    ov.y = __builtin_fmaf(__builtin_amdgcn_logf(p[4 * j + 1]), LN2_, nls);
    ov.z = __builtin_fmaf(__builtin_amdgcn_logf(p[4 * j + 2]), LN2_, nls);
    ov.w = __builtin_fmaf(__builtin_amdgcn_logf(p[4 * j + 3]), LN2_, nls);
    op[j] = ov;
  }
}

// ===========================================================================
// Fallback kernels for smaller workspaces (known-good R4/R0 structures).
// ===========================================================================
extern "C" __global__ void __launch_bounds__(64, 1)
hmm_recur2(const float* __restrict__ F, const float* __restrict__ ln_pi,
           const float* __restrict__ ln_A,
           float* __restrict__ alpha_out, float* __restrict__ beta_out) {
  const int lane = threadIdx.x;
  const int b   = blockIdx.x & (B_ - 1);
  const int dir = blockIdx.x >> 4;

  float pi[16];
#pragma unroll
  for (int i = 0; i < 16; ++i) pi[i] = __expf(ln_pi[lane * 16 + i]);
  const float offd = __expf(ln_A[1]);
  const float dmo  = __expf(ln_A[0]) - offd;
  const float ds   = dmo / offd;

  const float4* Frow = reinterpret_cast<const float4*>(F + (size_t)b * T_ * K_) + lane * 4;
  const int RS = K_ / 4;

  float4 eb[4][4];
  float inner[16];

  if (dir == 0) {
    float4* Arow = reinterpret_cast<float4*>(alpha_out + (size_t)b * T_ * K_) + lane * 4;
    {
      float4 h[4];
#pragma unroll
      for (int q = 0; q < 4; ++q) h[q] = Frow[q];
      const float* hf = reinterpret_cast<const float*>(h);
#pragma unroll
      for (int i = 0; i < 16; ++i) inner[i] = pi[i] * hf[i];
      float4 v0 = {inner[0], inner[1], inner[2], inner[3]},   v1 = {inner[4], inner[5], inner[6], inner[7]};
      float4 v2 = {inner[8], inner[9], inner[10], inner[11]}, v3 = {inner[12], inner[13], inner[14], inner[15]};
      Arow[0] = v0; Arow[1] = v1; Arow[2] = v2; Arow[3] = v3;
    }
#pragma unroll
    for (int j = 0; j < 4; ++j) {
      const float4* src = Frow + (size_t)(1 + j) * RS;
#pragma unroll
      for (int q = 0; q < 4; ++q) eb[j][q] = src[q];
    }
    for (int tt = 0; tt < T_ / 4; ++tt) {
#pragma unroll
      for (int j = 0; j < 4; ++j) {
        const int t = 1 + tt * 4 + j;
        const float S = wave_sum64_dpp(sum16(inner));
        const float s = ds * __builtin_amdgcn_rcpf(S);
        const float* ef = reinterpret_cast<const float*>(eb[j]);
#pragma unroll
        for (int i = 0; i < 16; ++i) inner[i] = ef[i] * __builtin_fmaf(s, inner[i], 1.0f);
        if (t < T_) {
          float4* dst = Arow + (size_t)t * RS;
          float4 v0 = {inner[0], inner[1], inner[2], inner[3]},   v1 = {inner[4], inner[5], inner[6], inner[7]};
          float4 v2 = {inner[8], inner[9], inner[10], inner[11]}, v3 = {inner[12], inner[13], inner[14], inner[15]};
          dst[0] = v0; dst[1] = v1; dst[2] = v2; dst[3] = v3;
        }
        const int rp = (t + 4 < T_) ? (t + 4) : (T_ - 1);
        const float4* src = Frow + (size_t)rp * RS;
#pragma unroll
        for (int q = 0; q < 4; ++q) eb[j][q] = src[q];
      }
    }
  } else {
    float4* Brow = reinterpret_cast<float4*>(beta_out + (size_t)b * T_ * K_) + lane * 4;
#pragma unroll
    for (int i = 0; i < 16; ++i) inner[i] = pi[i];
    {
      float4* dst = Brow + (size_t)(T_ - 1) * RS;
      float4 v0 = {inner[0], inner[1], inner[2], inner[3]},   v1 = {inner[4], inner[5], inner[6], inner[7]};
      float4 v2 = {inner[8], inner[9], inner[10], inner[11]}, v3 = {inner[12], inner[13], inner[14], inner[15]};
      dst[0] = v0; dst[1] = v1; dst[2] = v2; dst[3] = v3;
    }
#pragma unroll
    for (int j = 0; j < 4; ++j) {
      const float4* src = Frow + (size_t)(T_ - 1 - j) * RS;
#pragma unroll
      for (int q = 0; q < 4; ++q) eb[j][q] = src[q];
    }
    for (int kk = 0; kk < T_ / 4; ++kk) {
#pragma unroll
      for (int j = 0; j < 4; ++j) {
        const int k = kk * 4 + j;
        const float* ef = reinterpret_cast<const float*>(eb[j]);
        float u[16];
#pragma unroll
        for (int i = 0; i < 16; ++i) u[i] = ef[i] * inner[i];
        const float Su = wave_sum64_dpp(sum16(u));
        const float sB = ds * __builtin_amdgcn_rcpf(Su);
#pragma unroll
        for (int i = 0; i < 16; ++i) inner[i] = __builtin_fmaf(sB, u[i], 1.0f);
        if (k < T_ - 1) {
          float4* dst = Brow + (size_t)(T_ - 2 - k) * RS;
          float4 v0 = {inner[0], inner[1], inner[2], inner[3]},   v1 = {inner[4], inner[5], inner[6], inner[7]};
          float4 v2 = {inner[8], inner[9], inner[10], inner[11]}, v3 = {inner[12], inner[13], inner[14], inner[15]};
          dst[0] = v0; dst[1] = v1; dst[2] = v2; dst[3] = v3;
        }
        const int rp = (T_ - 1 - k - 4 > 0) ? (T_ - 1 - k - 4) : 0;
        const float4* src = Frow + (size_t)rp * RS;
#pragma unroll
        for (int q = 0; q < 4; ++q) eb[j][q] = src[q];
      }
    }
  }
}

extern "C" __global__ void __launch_bounds__(64, 1)
hmm_recur_fused(const float* __restrict__ obvs, const float* __restrict__ mu,
                const float* __restrict__ ln_sigma, const float* __restrict__ ln_pi,
                const float* __restrict__ ln_A,
                float* __restrict__ alpha_out, float* __restrict__ beta_out) {
  const int lane = threadIdx.x;
  const int b   = blockIdx.x & (B_ - 1);
  const int dir = blockIdx.x >> 4;

  __shared__ float so[T_];
  {
    const float4* src = reinterpret_cast<const float4*>(obvs + (size_t)b * T_);
    float4* dst = reinterpret_cast<float4*>(so);
#pragma unroll
    for (int j = 0; j < T_ / (4 * 64); ++j) dst[lane + j * 64] = src[lane + j * 64];
  }
  __syncthreads();

  float muv[16], niv[16], cc[16], pi[16];
#pragma unroll
  for (int i = 0; i < 16; ++i) {
    const int k = lane * 16 + i;
    const float m = mu[k], ls = ln_sigma[k];
    const float iv = __expf(-2.0f * ls);
    muv[i] = m; niv[i] = -0.5f * iv * LOG2E_; cc[i] = -ls * LOG2E_;
    pi[i] = __expf(ln_pi[k]);
  }
  const float offd = __expf(ln_A[1]);
  const float dmo  = __expf(ln_A[0]) - offd;

  if (dir == 0) {
    float a[16];
#pragma unroll
    for (int i = 0; i < 16; ++i) a[i] = (pi[i] - offd) / dmo;
    float4* dst = reinterpret_cast<float4*>(alpha_out + (size_t)b * T_ * K_) + lane * 4;
    float o = so[0];
    for (int t = 0; t < T_; ++t) {
      const float onext = so[(t + 1) & (T_ - 1)];
      float ah[16];
#pragma unroll
      for (int i = 0; i < 16; ++i) {
        const float d = o - muv[i];
        const float e = __builtin_amdgcn_exp2f(__builtin_fmaf(d * d, niv[i], cc[i]));
        ah[i] = e * __builtin_fmaf(a[i], dmo, offd);
      }
      const float S = warp_sum(sum16(ah));
      const float r = __builtin_amdgcn_rcpf(S);
#pragma unroll
      for (int i = 0; i < 16; ++i) a[i] = ah[i] * r;
      float4 v0 = {a[0], a[1], a[2], a[3]},   v1 = {a[4], a[5], a[6], a[7]};
      float4 v2 = {a[8], a[9], a[10], a[11]}, v3 = {a[12], a[13], a[14], a[15]};
      dst[0] = v0; dst[1] = v1; dst[2] = v2; dst[3] = v3;
      dst += K_ / 4;
      o = onext;
    }
  } else {
    float bc[16];
#pragma unroll
    for (int i = 0; i < 16; ++i) bc[i] = pi[i];
    const float sumA = __builtin_fmaf((float)K_, offd, dmo);
    const float q = offd / sumA;
    float4* dst = reinterpret_cast<float4*>(beta_out + ((size_t)b * T_ + (T_ - 1)) * K_) + lane * 4;
    {
      float4 v0 = {bc[0], bc[1], bc[2], bc[3]},   v1 = {bc[4], bc[5], bc[6], bc[7]};
      float4 v2 = {bc[8], bc[9], bc[10], bc[11]}, v3 = {bc[12], bc[13], bc[14], bc[15]};
      dst[0] = v0; dst[1] = v1; dst[2] = v2; dst[3] = v3;
    }
    float o = so[T_ - 1];
    for (int t = T_ - 2; t >= 0; --t) {
      const float onext = so[t];
      float u[16];
#pragma unroll
      for (int i = 0; i < 16; ++i) {
        const float d = o - muv[i];
        const float e = __builtin_amdgcn_exp2f(__builtin_fmaf(d * d, niv[i], cc[i]));
        u[i] = e * bc[i];
      }
      const float Su = warp_sum(sum16(u));
      const float r = __builtin_amdgcn_rcpf(Su * sumA);
      const float coef = dmo * r;
#pragma unroll
      for (int i = 0; i < 16; ++i) bc[i] = __builtin_fmaf(u[i], coef, q);
      dst -= K_ / 4;
      float4 v0 = {bc[0], bc[1], bc[2], bc[3]},   v1 = {bc[4], bc[5], bc[6], bc[7]};
      float4 v2 = {bc[8], bc[9], bc[10], bc[11]}, v3 = {bc[12], bc[13], bc[14], bc[15]};
      dst[0] = v0; dst[1] = v1; dst[2] = v2; dst[3] = v3;
      o = onext;
    }
  }
}

extern "C" __global__ void __launch_bounds__(64, 1)
hmm_bwd_gamma(const float* __restrict__ obvs, const float* __restrict__ mu,
              const float* __restrict__ ln_sigma, const float* __restrict__ ln_pi,
              const float* __restrict__ ln_A, float* __restrict__ io) {
  const int lane = threadIdx.x;
  const int b = blockIdx.x;

  __shared__ float so[T_];
  {
    const float4* src = reinterpret_cast<const float4*>(obvs + (size_t)b * T_);
    float4* dst = reinterpret_cast<float4*>(so);
#pragma unroll
    for (int j = 0; j < T_ / (4 * 64); ++j) dst[lane + j * 64] = src[lane + j * 64];
  }
  __syncthreads();

  float muv[16], niv[16], cc[16], pi[16];
#pragma unroll
  for (int i = 0; i < 16; ++i) {
    const int k = lane * 16 + i;
    const float m = mu[k], ls = ln_sigma[k];
    const float iv = __expf(-2.0f * ls);
    muv[i] = m; niv[i] = -0.5f * iv * LOG2E_; cc[i] = -ls * LOG2E_;
    pi[i] = __expf(ln_pi[k]);
  }
  const float offd = __expf(ln_A[1]);
  const float dmo  = __expf(ln_A[0]) - offd;
  const float sumA = __builtin_fmaf((float)K_, offd, dmo);
  const float q = offd / sumA;

  float bc[16];
#pragma unroll
  for (int i = 0; i < 16; ++i) bc[i] = pi[i];

  float4* gp = reinterpret_cast<float4*>(io + ((size_t)b * T_ + (T_ - 1)) * K_) + lane * 4;
  {
    float4 a0 = gp[0], a1 = gp[1], a2 = gp[2], a3 = gp[3];
    float p[16] = {a0.x * bc[0],  a0.y * bc[1],  a0.z * bc[2],  a0.w * bc[3],
                   a1.x * bc[4],  a1.y * bc[5],  a1.z * bc[6],  a1.w * bc[7],
                   a2.x * bc[8],  a2.y * bc[9],  a2.z * bc[10], a2.w * bc[11],
                   a3.x * bc[12], a3.y * bc[13], a3.z * bc[14], a3.w * bc[15]};
    const float Sp  = warp_sum(sum16(p));
    const float nls = -__builtin_amdgcn_logf(Sp) * LN2_;
    float g[16];
#pragma unroll
    for (int i = 0; i < 16; ++i) g[i] = __builtin_fmaf(__builtin_amdgcn_logf(p[i]), LN2_, nls);
    float4 v0 = {g[0], g[1], g[2], g[3]},   v1 = {g[4], g[5], g[6], g[7]};
    float4 v2 = {g[8], g[9], g[10], g[11]}, v3 = {g[12], g[13], g[14], g[15]};
    gp[0] = v0; gp[1] = v1; gp[2] = v2; gp[3] = v3;
  }
  float o = so[T_ - 1];
  for (int t = T_ - 2; t >= 0; --t) {
    const float onext = so[t];
    gp -= K_ / 4;
    float4 a0 = gp[0], a1 = gp[1], a2 = gp[2], a3 = gp[3];
    float u[16];
#pragma unroll
    for (int i = 0; i < 16; ++i) {
      const float d = o - muv[i];
      const float e = __builtin_amdgcn_exp2f(__builtin_fmaf(d * d, niv[i], cc[i]));
      u[i] = e * bc[i];
    }
    const float Su = warp_sum(sum16(u));
    const float r = __builtin_amdgcn_rcpf(Su * sumA);
    const float coef = dmo * r;
#pragma unroll
    for (int i = 0; i < 16; ++i) bc[i] = __builtin_fmaf(u[i], coef, q);
    float p[16] = {a0.x * bc[0],  a0.y * bc[1],  a0.z * bc[2],  a0.w * bc[3],
                   a1.x * bc[4],  a1.y * bc[5],  a1.z * bc[6],  a1.w * bc[7],
                   a2.x * bc[8],  a2.y * bc[9],  a2.z * bc[10], a2.w * bc[11],
                   a3.x * bc[12], a3.y * bc[13], a3.z * bc[14], a3.w * bc[15]};
    const float Sp  = warp_sum(sum16(p));
    const float nls = -__builtin_amdgcn_logf(Sp) * LN2_;
    float g[16];
#pragma unroll
    for (int i = 0; i < 16; ++i) g[i] = __builtin_fmaf(__builtin_amdgcn_logf(p[i]), LN2_, nls);
    float4 v0 = {g[0], g[1], g[2], g[3]},   v1 = {g[4], g[5], g[6], g[7]};
    float4 v2 = {g[8], g[9], g[10], g[11]}, v3 = {g[12], g[13], g[14], g[15]};
    gp[0] = v0; gp[1] = v1; gp[2] = v2; gp[3] = v3;
    o = onext;
  }
}

extern "C" void kernel_launch(void* const* d_in, const int* in_sizes, int n_in,
                              void* d_out, int out_size, void* d_ws, size_t ws_size,
                              hipStream_t stream) {
  const float* obvs     = (const float*)d_in[0];
  const float* mu       = (const float*)d_in[1];
  const float* ln_sigma = (const float*)d_in[2];
  const float* ln_pi    = (const float*)d_in[3];
  const float* ln_A     = (const float*)d_in[4];
  float* out = (float*)d_out;

  const size_t plane  = (size_t)B_ * T_ * K_;          // 16.7M elements
  const size_t planeB = plane * sizeof(float);         // 64 MiB
  const size_t smallN = 2 * (size_t)B_ * T_;           // sf + sb elements
  const size_t needNew = 2 * planeB + smallN * sizeof(float);

  if (ws_size >= needNew) {
    float* sf   = (float*)d_ws;
    float* sb   = sf + (size_t)B_ * T_;
    float* F    = sb + (size_t)B_ * T_;
    float* beta = F + plane;
    hipLaunchKernelGGL(hmm_emit, dim3(B_ * T_), dim3(256), 0, stream,
                       obvs, mu, ln_sigma, ln_A, F);
    hipLaunchKernelGGL(hmm_scal, dim3(32), dim3(64), 0, stream,
                       F, ln_pi, ln_A, sf, sb, out, beta);
    hipLaunchKernelGGL(hmm_recon, dim3(2 * B_ * NC_), dim3(256), 0, stream,
                       F, sf, sb, out, beta);
    hipLaunchKernelGGL(hmm_gamma, dim3(B_ * T_ / 4), dim3(256), 0, stream,
                       out, beta, out);
  } else if (ws_size >= 2 * planeB) {
    float* F    = (float*)d_ws;
    float* beta = F + plane;
    hipLaunchKernelGGL(hmm_emit, dim3(B_ * T_), dim3(256), 0, stream,
                       obvs, mu, ln_sigma, ln_A, F);
    hipLaunchKernelGGL(hmm_recur2, dim3(32), dim3(64), 0, stream,
                       F, ln_pi, ln_A, out, beta);
    hipLaunchKernelGGL(hmm_gamma, dim3(B_ * T_ / 4), dim3(256), 0, stream,
                       out, beta, out);
  } else if (ws_size >= planeB) {
    float* beta = (float*)d_ws;
    hipLaunchKernelGGL(hmm_recur_fused, dim3(32), dim3(64), 0, stream,
                       obvs, mu, ln_sigma, ln_pi, ln_A, out, beta);
    hipLaunchKernelGGL(hmm_gamma, dim3(B_ * T_ / 4), dim3(256), 0, stream,
                       out, beta, out);
  } else {
    hipLaunchKernelGGL(hmm_recur_fused, dim3(16), dim3(64), 0, stream,
                       obvs, mu, ln_sigma, ln_pi, ln_A, out, out);
    hipLaunchKernelGGL(hmm_bwd_gamma, dim3(16), dim3(64), 0, stream,
                       obvs, mu, ln_sigma, ln_pi, ln_A, out);
  }
}